// Round 3
// baseline (635.175 us; speedup 1.0000x reference)
//
#include <hip/hip_runtime.h>
#include <math.h>

#define BB 64
#define LL 1024
#define DD 1024

__device__ __forceinline__ float artanh_c(float x){
  x = fminf(fmaxf(x, -1.f + 1e-7f), 1.f - 1e-7f);
  return 0.5f * __logf((1.f + x) / (1.f - x));
}

__device__ __forceinline__ float wave_sum(float v){
  #pragma unroll
  for(int o = 32; o > 0; o >>= 1) v += __shfl_down(v, o, 64);
  return v;
}

// block reduce for blockDim.x = 1024 (16 waves); red must be >=16 floats
__device__ __forceinline__ float block_sum(float v, float* red){
  v = wave_sum(v);
  int wid = threadIdx.x >> 6, lane = threadIdx.x & 63;
  __syncthreads();
  if(lane == 0) red[wid] = v;
  __syncthreads();
  if(wid == 0){
    float t = lane < 16 ? red[lane] : 0.f;
    #pragma unroll
    for(int o = 8; o > 0; o >>= 1) t += __shfl_down(t, o, 64);
    if(lane == 0) red[0] = t;
  }
  __syncthreads();
  return red[0];
}

__device__ __forceinline__ float block_max(float v, float* red){
  #pragma unroll
  for(int o = 32; o > 0; o >>= 1) v = fmaxf(v, __shfl_down(v, o, 64));
  int wid = threadIdx.x >> 6, lane = threadIdx.x & 63;
  __syncthreads();
  if(lane == 0) red[wid] = v;
  __syncthreads();
  if(wid == 0){
    float t = lane < 16 ? red[lane] : -INFINITY;
    #pragma unroll
    for(int o = 8; o > 0; o >>= 1) t = fmaxf(t, __shfl_down(t, o, 64));
    if(lane == 0) red[0] = t;
  }
  __syncthreads();
  return red[0];
}

// K1: q[b,e] = dot(query[b,:], Win[e,:]); wave owns e, loops 16 b; Win row in regs
__global__ void k_qproj(const float* __restrict__ query, const float* __restrict__ Win,
                        float* __restrict__ q){
  int wave = threadIdx.x >> 6, lane = threadIdx.x & 63;
  int e = blockIdx.x * 4 + wave;
  int b0 = blockIdx.y * 16;
  const float4* Wr = (const float4*)(Win + (size_t)e * DD);
  float4 w[4];
  #pragma unroll
  for(int j = 0; j < 4; j++) w[j] = Wr[j * 64 + lane];
  for(int bb = 0; bb < 16; bb++){
    int b = b0 + bb;
    const float4* qr = (const float4*)(query + (size_t)b * DD);
    float acc = 0.f;
    #pragma unroll
    for(int j = 0; j < 4; j++){
      float4 v = qr[j * 64 + lane];
      acc += w[j].x * v.x + w[j].y * v.y + w[j].z * v.z + w[j].w * v.w;
    }
    acc = wave_sum(acc);
    if(lane == 0) q[b * DD + e] = acc;
  }
}

// K2: scores[b,l] = dot(q[b,:], ctx[b,l,:]); wave per (b,l) row, coalesced float4
__global__ void k_scores(const float* __restrict__ qv, const float* __restrict__ ctx,
                         float* __restrict__ scores){
  int b = blockIdx.y;
  int wave = threadIdx.x >> 6, lane = threadIdx.x & 63;
  int l = blockIdx.x * 4 + wave;
  __shared__ float4 qs4[DD / 4];
  if(threadIdx.x < 256) qs4[threadIdx.x] = ((const float4*)(qv + (size_t)b * DD))[threadIdx.x];
  __syncthreads();
  const float4* cr = (const float4*)(ctx + ((size_t)b * LL + l) * DD);
  float acc = 0.f;
  #pragma unroll
  for(int it = 0; it < 4; it++){
    int idx = it * 64 + lane;
    float4 v = cr[idx];
    float4 qq = qs4[idx];
    acc += qq.x * v.x + qq.y * v.y + qq.z * v.z + qq.w * v.w;
  }
  acc = wave_sum(acc);
  if(lane == 0) scores[b * LL + l] = acc;
}

// K3: per-b softmax over L, then aw = project(expmap0(aw)); bt = project(expmap0(exp(-ab*dt)))
__global__ void k_softmax_tr(const float* __restrict__ scores, const float* __restrict__ dt,
                             const float* __restrict__ ab, const float* __restrict__ cp,
                             float* __restrict__ awt, float* __restrict__ aw_out,
                             float* __restrict__ btt, float* __restrict__ btn){
  __shared__ float red[16];
  int b = blockIdx.x, tid = threadIdx.x;
  float c = cp[0], sc = sqrtf(c), maxn = (1.f - 4e-3f) / sc;
  float s = scores[b * LL + tid];
  float m = block_max(s, red);
  float e = __expf(s - m);
  float Z = block_sum(e, red);
  float aw = e / Z;
  float S = block_sum(aw * aw, red);
  float n = fmaxf(sqrtf(S), 1e-15f);
  float tau = tanhf(sc * n) / (sc * n);
  float n1 = fmaxf(tau * sqrtf(S), 1e-15f);
  float s1 = n1 > maxn ? maxn / n1 : 1.f;
  float awf = tau * s1 * aw;
  awt[b * LL + tid] = awf;
  aw_out[b * LL + tid] = awf;
  float btv = __expf(-ab[b] * dt[b * LL + tid]);
  float S2 = block_sum(btv * btv, red);
  float n2 = fmaxf(sqrtf(S2), 1e-15f);
  float tau2 = tanhf(sc * n2) / (sc * n2);
  float nb = fmaxf(tau2 * sqrtf(S2), 1e-15f);
  float s2 = nb > maxn ? maxn / nb : 1.f;
  float btf = tau2 * s2 * btv;
  btt[b * LL + tid] = btf;
  if(tid == 0) btn[b] = fmaxf(tau2 * s2 * sqrtf(S2), 1e-15f);
}

// K4: per-row partial sums over l-chunk of 64; thread owns d-quad (float4);
// atomicAdd into stats[b][6][DD] (pre-zeroed)
__global__ void k_stats(const float* __restrict__ ctx, const float* __restrict__ awt,
                        const float* __restrict__ btt, float* __restrict__ stats){
  int tid = threadIdx.x;
  int b = blockIdx.x;
  int l0 = blockIdx.y * 64;
  __shared__ float ws_[64], bs_[64];
  if(tid < 64){ ws_[tid] = awt[b * LL + l0 + tid]; bs_[tid] = btt[b * LL + l0 + tid]; }
  __syncthreads();
  const float4* cpx = (const float4*)(ctx + ((size_t)b * LL + l0) * DD) + tid;
  float r2[4] = {0,0,0,0}, p2[4] = {0,0,0,0};
  float s3p[4] = {0,0,0,0}, s3m[4] = {0,0,0,0};
  float s5p[4] = {0,0,0,0}, s5m[4] = {0,0,0,0};
  #pragma unroll 4
  for(int i = 0; i < 64; i++){
    float4 rv = cpx[(size_t)i * (DD / 4)];
    float w = ws_[i], bt = bs_[i];
    float rr[4] = {rv.x, rv.y, rv.z, rv.w};
    #pragma unroll
    for(int c = 0; c < 4; c++){
      float r = rr[c];
      float p = w * r;
      r2[c] = fmaf(r, r, r2[c]);
      p2[c] = fmaf(p, p, p2[c]);
      float pb = p * bt;
      float pb2 = pb * pb;
      float p2bt = (p * p) * bt;
      if(r > 0.f){ s3p[c] += pb2; s5p[c] += p2bt; } else { s3m[c] += pb2; s5m[c] += p2bt; }
    }
  }
  int d = tid * 4;
  float* base = stats + (size_t)b * 6 * DD + d;
  #pragma unroll
  for(int c = 0; c < 4; c++){
    atomicAdd(base + 0 * DD + c, r2[c]);
    atomicAdd(base + 1 * DD + c, p2[c]);
    atomicAdd(base + 2 * DD + c, s3p[c]);
    atomicAdd(base + 3 * DD + c, s3m[c]);
    atomicAdd(base + 4 * DD + c, s5p[c]);
    atomicAdd(base + 5 * DD + c, s5m[c]);
  }
}

// K5: per-row scalar chain -> U, Vp, Vm (exact reference EPS/clip semantics)
__global__ void k_finish(const float* __restrict__ stats, const float* __restrict__ ae,
                         const float* __restrict__ btn, const float* __restrict__ cp,
                         float* __restrict__ rowsc){
  int row = blockIdx.x * 256 + threadIdx.x;     // row = b*DD + d
  int b = row >> 10;
  int d = row & (DD - 1);
  float c = cp[0], sc = sqrtf(c), maxn = (1.f - 4e-3f) / sc;
  const float* st = stats + (size_t)b * 6 * DD + d;
  float r2 = st[0], p2 = st[DD], s3p = st[2 * DD], s3m = st[3 * DD], s5p = st[4 * DD], s5m = st[5 * DD];
  float sp2 = sqrtf(p2);
  // mobius_pointwise_mul(aw, ctx_col) + project  -> mix = beta * p
  float xn  = fmaxf(sqrtf(r2), 1e-15f);
  float wxn = fmaxf(sp2, 1e-15f);
  float at1 = artanh_c(sc * xn);
  float alpha = tanhf(wxn / xn * at1) / (wxn * sc);
  float n1 = fmaxf(alpha * sp2, 1e-15f);
  float beta = alpha * (n1 > maxn ? maxn / n1 : 1.f);
  // mobius_pointwise_mul(ae, mix) + project  -> tmp = g * p
  float aeb = ae[b];
  float mixn_raw = beta * sp2;
  float xn2  = fmaxf(mixn_raw, 1e-15f);
  float wxn2 = fmaxf(fabsf(aeb) * mixn_raw, 1e-15f);
  float at2 = artanh_c(sc * xn2);
  float coef_t = tanhf(wxn2 / xn2 * at2) * aeb * beta / (wxn2 * sc);
  float n2 = fmaxf(fabsf(coef_t) * sp2, 1e-15f);
  float g = coef_t * (n2 > maxn ? maxn / n2 : 1.f);
  // mobius_pointwise_mul(tmp, bt) + project  -> tmp2 = k * (p .* bt)
  float s3 = s3p + s3m;
  float sq3 = sqrtf(s3);
  float xn3 = btn[b];
  float wxn3 = fmaxf(fabsf(g) * sq3, 1e-15f);
  float at3 = artanh_c(sc * xn3);
  float coef2 = tanhf(wxn3 / xn3 * at3) * g / (wxn3 * sc);
  float n3 = fmaxf(fabsf(coef2) * sq3, 1e-15f);
  float k = coef2 * (n3 > maxn ? maxn / n3 : 1.f);
  // term2 = relu(k * p .* bt): nonzero where sign(r) == sign(k)
  bool kp = k > 0.f;
  float ssel  = kp ? s3p : s3m;
  float s5sel = kp ? s5p : s5m;
  float y2 = k * k * ssel;
  float xy = beta * k * s5sel;
  float x2 = beta * beta * p2;
  float A  = 1.f + 2.f * c * xy + c * y2;
  float Bc = 1.f - c * x2;
  float den = 1.f + 2.f * c * xy + c * c * x2 * y2;
  den = fmaxf(den, 1e-15f);
  float U0 = A * beta / den;
  float V0 = Bc * k / den;
  float nf2 = U0 * U0 * p2 + 2.f * U0 * V0 * s5sel + V0 * V0 * ssel;
  float nf = fmaxf(sqrtf(nf2), 1e-15f);
  float s4 = nf > maxn ? maxn / nf : 1.f;
  float U = U0 * s4, V = V0 * s4;
  float4* out4 = (float4*)(rowsc + (size_t)row * 4);
  *out4 = make_float4(U, kp ? V : 0.f, kp ? 0.f : V, 0.f);
}

// K6 (fused): per 16-row ctx chunk staged in LDS:
//   phase 1: colsum per row (wave-per-row) -> lam (local + global)
//   phase 2: nom partial per d-quad, atomicAdd (nom pre-zeroed)
__global__ __launch_bounds__(256) void k_mixagg(const float* __restrict__ ctx,
                         const float* __restrict__ awt, const float* __restrict__ btt,
                         const float* __restrict__ rowsc, const float* __restrict__ cp,
                         float* __restrict__ lam_out, float* __restrict__ nom){
  __shared__ float4 cs4[16 * 256];
  __shared__ float aw_s[16], bt_s[16], lam_s[16];
  int b = blockIdx.y;
  int l0 = blockIdx.x * 16;
  int tid = threadIdx.x, wave = tid >> 6, lane = tid & 63;
  float c = cp[0];
  // stage 16 ctx rows (coalesced float4)
  const float4* cg = (const float4*)(ctx + ((size_t)b * LL + l0) * DD);
  #pragma unroll
  for(int r = 0; r < 16; r++) cs4[r * 256 + tid] = cg[r * 256 + tid];
  if(tid < 16){ aw_s[tid] = awt[b * LL + l0 + tid]; bt_s[tid] = btt[b * LL + l0 + tid]; }
  // preload rowsc: wave-layout (phase 1) d=(it*64+lane)*4+j
  float U1[4][4], Vp1[4][4], Vm1[4][4];
  const float4* rp = (const float4*)rowsc + (size_t)b * DD;
  #pragma unroll
  for(int it = 0; it < 4; it++){
    int d4 = it * 64 + lane;
    #pragma unroll
    for(int j = 0; j < 4; j++){
      float4 t = rp[d4 * 4 + j];
      U1[it][j] = t.x; Vp1[it][j] = t.y; Vm1[it][j] = t.z;
    }
  }
  // preload rowsc: quad-layout (phase 2) d=tid*4+j
  float U2[4], Vp2[4], Vm2[4];
  #pragma unroll
  for(int j = 0; j < 4; j++){
    float4 t = rp[tid * 4 + j];
    U2[j] = t.x; Vp2[j] = t.y; Vm2[j] = t.z;
  }
  __syncthreads();
  // phase 1: wave w handles rows w, w+4, w+8, w+12
  #pragma unroll
  for(int rr = 0; rr < 4; rr++){
    int r = wave + rr * 4;
    float w = aw_s[r], bt = bt_s[r];
    float acc = 0.f;
    #pragma unroll
    for(int it = 0; it < 4; it++){
      float4 rv = cs4[r * 256 + it * 64 + lane];
      float rx[4] = {rv.x, rv.y, rv.z, rv.w};
      #pragma unroll
      for(int j = 0; j < 4; j++){
        float rc = rx[j];
        float p = w * rc;
        float t = rc > 0.f ? Vp1[it][j] : Vm1[it][j];
        float mv = p * (U1[it][j] + bt * t);
        acc = fmaf(mv, mv, acc);
      }
    }
    acc = wave_sum(acc);
    if(lane == 0){
      float lv = 2.f / fmaxf(1.f - c * acc, 1e-15f);
      lam_s[r] = lv;
      lam_out[b * LL + l0 + r] = lv;
    }
  }
  __syncthreads();
  // phase 2: thread owns d-quad, accumulate nom over 16 rows
  float acc2[4] = {0, 0, 0, 0};
  #pragma unroll 4
  for(int r = 0; r < 16; r++){
    float w = aw_s[r], bt = bt_s[r], lv = lam_s[r];
    float4 rv = cs4[r * 256 + tid];
    float rx[4] = {rv.x, rv.y, rv.z, rv.w};
    #pragma unroll
    for(int j = 0; j < 4; j++){
      float rc = rx[j];
      float p = w * rc;
      float t = rc > 0.f ? Vp2[j] : Vm2[j];
      float mv = p * (U2[j] + bt * t);
      acc2[j] = fmaf(lv, mv, acc2[j]);
    }
  }
  #pragma unroll
  for(int j = 0; j < 4; j++) atomicAdd(nom + (size_t)b * DD + tid * 4 + j, acc2[j]);
}

// K7a: den from lam; tm = nom/den; midpoint half-scalar-mul; logmap0; combined = [mixl, q]
__global__ void k_mid(const float* __restrict__ nom, const float* __restrict__ lam,
                      const float* __restrict__ qv, const float* __restrict__ cp,
                      float* __restrict__ comb){
  __shared__ float red[16];
  int b = blockIdx.x, tid = threadIdx.x;
  float c = cp[0], sc = sqrtf(c);
  float lv = lam[b * LL + tid];
  float dsum = block_sum(lv - 1.f, red);
  float den = dsum >= 0.f ? fmaxf(dsum, 1e-10f) : fminf(dsum, -1e-10f);
  float tm = nom[b * DD + tid] / den;
  float S = block_sum(tm * tm, red);
  float n = fmaxf(sqrtf(S), 1e-15f);
  float at = artanh_c(sc * n);
  float mu = tanhf(0.5f * at) / (sc * n);
  float n2 = fmaxf(mu * sqrtf(S), 1e-15f);
  float nu = artanh_c(sc * n2) / (sc * n2);
  comb[b * 2 * DD + tid] = nu * mu * tm;
  comb[b * 2 * DD + DD + tid] = qv[b * DD + tid];
}

// K7b: out[b,d] = tanh(dot(comb[b,:], Wout[d,:])); wave owns d, loops 16 b; Wout row in regs
__global__ void k_out(const float* __restrict__ comb, const float* __restrict__ Wout,
                      float* __restrict__ outp){
  int wave = threadIdx.x >> 6, lane = threadIdx.x & 63;
  int d = blockIdx.x * 4 + wave;
  int b0 = blockIdx.y * 16;
  const float4* Wr = (const float4*)(Wout + (size_t)d * 2 * DD);
  float4 w[8];
  #pragma unroll
  for(int j = 0; j < 8; j++) w[j] = Wr[j * 64 + lane];
  for(int bb = 0; bb < 16; bb++){
    int b = b0 + bb;
    const float4* cb = (const float4*)(comb + (size_t)b * 2 * DD);
    float acc = 0.f;
    #pragma unroll
    for(int j = 0; j < 8; j++){
      float4 v = cb[j * 64 + lane];
      acc += w[j].x * v.x + w[j].y * v.y + w[j].z * v.z + w[j].w * v.w;
    }
    acc = wave_sum(acc);
    if(lane == 0) outp[b * DD + d] = tanhf(acc);
  }
}

extern "C" void kernel_launch(void* const* d_in, const int* in_sizes, int n_in,
                              void* d_out, int out_size, void* d_ws, size_t ws_size,
                              hipStream_t stream) {
  const float* query = (const float*)d_in[0];
  const float* ctx   = (const float*)d_in[1];
  const float* dt    = (const float*)d_in[2];
  const float* cp    = (const float*)d_in[3];
  const float* Win   = (const float*)d_in[4];
  const float* Wout  = (const float*)d_in[5];
  const float* ae    = (const float*)d_in[6];
  const float* ab    = (const float*)d_in[7];
  float* out = (float*)d_out;
  float* ws  = (float*)d_ws;

  // ws layout (floats)
  float* q_      = ws;                 // 65536
  float* awt_    = ws + 65536;         // 65536
  float* btt_    = ws + 131072;        // 65536
  float* btn_    = ws + 196608;        // 64
  float* scores_ = ws + 196672;        // 65536  (reused as lam)
  float* stats_  = ws + 262208;        // 393216 [b][6][D] (reused as comb)
  float* nom_    = ws + 655424;        // 65536
  float* rowsc_  = ws + 720960;        // 262144 [row][4] = (U,Vp,Vm,0)
  float* lam_  = scores_;
  float* comb_ = stats_;

  // zero only the atomic accumulators: stats | nom (contiguous)
  hipMemsetAsync(stats_, 0, (size_t)(393216 + 65536) * sizeof(float), stream);

  k_qproj     <<<dim3(256, 4),  256,  0, stream>>>(query, Win, q_);
  k_scores    <<<dim3(256, BB), 256,  0, stream>>>(q_, ctx, scores_);
  k_softmax_tr<<<BB,            1024, 0, stream>>>(scores_, dt, ab, cp, awt_, out + BB * DD, btt_, btn_);
  k_stats     <<<dim3(BB, 16),  256,  0, stream>>>(ctx, awt_, btt_, stats_);
  k_finish    <<<256,           256,  0, stream>>>(stats_, ae, btn_, cp, rowsc_);
  k_mixagg    <<<dim3(64, BB),  256,  0, stream>>>(ctx, awt_, btt_, rowsc_, cp, lam_, nom_);
  k_mid       <<<BB,            1024, 0, stream>>>(nom_, lam_, q_, cp, comb_);
  k_out       <<<dim3(256, 4),  256,  0, stream>>>(comb_, Wout, out);
}

// Round 4
// 599.291 us; speedup vs baseline: 1.0599x; 1.0599x over previous
//
#include <hip/hip_runtime.h>
#include <math.h>

#define BB 64
#define LL 1024
#define DD 1024

typedef __attribute__((ext_vector_type(4))) _Float16 half4;

__device__ __forceinline__ float artanh_c(float x){
  x = fminf(fmaxf(x, -1.f + 1e-7f), 1.f - 1e-7f);
  return 0.5f * __logf((1.f + x) / (1.f - x));
}

__device__ __forceinline__ float wave_sum(float v){
  #pragma unroll
  for(int o = 32; o > 0; o >>= 1) v += __shfl_down(v, o, 64);
  return v;
}

// block reduce for blockDim.x = 1024 (16 waves); red must be >=16 floats
__device__ __forceinline__ float block_sum(float v, float* red){
  v = wave_sum(v);
  int wid = threadIdx.x >> 6, lane = threadIdx.x & 63;
  __syncthreads();
  if(lane == 0) red[wid] = v;
  __syncthreads();
  if(wid == 0){
    float t = lane < 16 ? red[lane] : 0.f;
    #pragma unroll
    for(int o = 8; o > 0; o >>= 1) t += __shfl_down(t, o, 64);
    if(lane == 0) red[0] = t;
  }
  __syncthreads();
  return red[0];
}

__device__ __forceinline__ float block_max(float v, float* red){
  #pragma unroll
  for(int o = 32; o > 0; o >>= 1) v = fmaxf(v, __shfl_down(v, o, 64));
  int wid = threadIdx.x >> 6, lane = threadIdx.x & 63;
  __syncthreads();
  if(lane == 0) red[wid] = v;
  __syncthreads();
  if(wid == 0){
    float t = lane < 16 ? red[lane] : -INFINITY;
    #pragma unroll
    for(int o = 8; o > 0; o >>= 1) t = fmaxf(t, __shfl_down(t, o, 64));
    if(lane == 0) red[0] = t;
  }
  __syncthreads();
  return red[0];
}

// K1: q[b,e] = dot(query[b,:], Win[e,:]); wave owns e, loops 16 b; Win row in regs
__global__ void k_qproj(const float* __restrict__ query, const float* __restrict__ Win,
                        float* __restrict__ q){
  int wave = threadIdx.x >> 6, lane = threadIdx.x & 63;
  int e = blockIdx.x * 4 + wave;
  int b0 = blockIdx.y * 16;
  const float4* Wr = (const float4*)(Win + (size_t)e * DD);
  float4 w[4];
  #pragma unroll
  for(int j = 0; j < 4; j++) w[j] = Wr[j * 64 + lane];
  for(int bb = 0; bb < 16; bb++){
    int b = b0 + bb;
    const float4* qr = (const float4*)(query + (size_t)b * DD);
    float acc = 0.f;
    #pragma unroll
    for(int j = 0; j < 4; j++){
      float4 v = qr[j * 64 + lane];
      acc += w[j].x * v.x + w[j].y * v.y + w[j].z * v.z + w[j].w * v.w;
    }
    acc = wave_sum(acc);
    if(lane == 0) q[b * DD + e] = acc;
  }
}

// K2: scores[b,l] = dot(q[b,:], ctx[b,l,:]); wave per (b,l) row, coalesced float4.
// Side effect: emit fp16 copy of ctx (each row touched exactly once).
__global__ void k_scores(const float* __restrict__ qv, const float* __restrict__ ctx,
                         float* __restrict__ scores, _Float16* __restrict__ ctx16){
  int b = blockIdx.y;
  int wave = threadIdx.x >> 6, lane = threadIdx.x & 63;
  int l = blockIdx.x * 4 + wave;
  __shared__ float4 qs4[DD / 4];
  if(threadIdx.x < 256) qs4[threadIdx.x] = ((const float4*)(qv + (size_t)b * DD))[threadIdx.x];
  __syncthreads();
  const float4* cr = (const float4*)(ctx + ((size_t)b * LL + l) * DD);
  half4* c16 = (half4*)(ctx16 + ((size_t)b * LL + l) * DD);
  float acc = 0.f;
  #pragma unroll
  for(int it = 0; it < 4; it++){
    int idx = it * 64 + lane;
    float4 v = cr[idx];
    float4 qq = qs4[idx];
    acc += qq.x * v.x + qq.y * v.y + qq.z * v.z + qq.w * v.w;
    half4 h;
    h.x = (_Float16)v.x; h.y = (_Float16)v.y; h.z = (_Float16)v.z; h.w = (_Float16)v.w;
    c16[idx] = h;
  }
  acc = wave_sum(acc);
  if(lane == 0) scores[b * LL + l] = acc;
}

// K3: per-b softmax over L, then aw = project(expmap0(aw)); bt = project(expmap0(exp(-ab*dt)))
__global__ void k_softmax_tr(const float* __restrict__ scores, const float* __restrict__ dt,
                             const float* __restrict__ ab, const float* __restrict__ cp,
                             float* __restrict__ awt, float* __restrict__ aw_out,
                             float* __restrict__ btt, float* __restrict__ btn){
  __shared__ float red[16];
  int b = blockIdx.x, tid = threadIdx.x;
  float c = cp[0], sc = sqrtf(c), maxn = (1.f - 4e-3f) / sc;
  float s = scores[b * LL + tid];
  float m = block_max(s, red);
  float e = __expf(s - m);
  float Z = block_sum(e, red);
  float aw = e / Z;
  float S = block_sum(aw * aw, red);
  float n = fmaxf(sqrtf(S), 1e-15f);
  float tau = tanhf(sc * n) / (sc * n);
  float n1 = fmaxf(tau * sqrtf(S), 1e-15f);
  float s1 = n1 > maxn ? maxn / n1 : 1.f;
  float awf = tau * s1 * aw;
  awt[b * LL + tid] = awf;
  aw_out[b * LL + tid] = awf;
  float btv = __expf(-ab[b] * dt[b * LL + tid]);
  float S2 = block_sum(btv * btv, red);
  float n2 = fmaxf(sqrtf(S2), 1e-15f);
  float tau2 = tanhf(sc * n2) / (sc * n2);
  float nb = fmaxf(tau2 * sqrtf(S2), 1e-15f);
  float s2 = nb > maxn ? maxn / nb : 1.f;
  float btf = tau2 * s2 * btv;
  btt[b * LL + tid] = btf;
  if(tid == 0) btn[b] = fmaxf(tau2 * s2 * sqrtf(S2), 1e-15f);
}

// K4: per-row partial sums over l-chunk of 128 from fp16 ctx; thread owns d-quad;
// atomicAdd into stats[b][6][DD] (pre-zeroed)
__global__ __launch_bounds__(256) void k_stats(const _Float16* __restrict__ ctx16,
                        const float* __restrict__ awt,
                        const float* __restrict__ btt, float* __restrict__ stats){
  int tid = threadIdx.x;
  int b = blockIdx.x;
  int l0 = blockIdx.y * 128;
  __shared__ float ws_[128], bs_[128];
  if(tid < 128){ ws_[tid] = awt[b * LL + l0 + tid]; bs_[tid] = btt[b * LL + l0 + tid]; }
  __syncthreads();
  const half4* cpx = (const half4*)(ctx16 + ((size_t)b * LL + l0) * DD) + tid;
  float r2[4] = {0,0,0,0}, p2[4] = {0,0,0,0};
  float s3p[4] = {0,0,0,0}, s3m[4] = {0,0,0,0};
  float s5p[4] = {0,0,0,0}, s5m[4] = {0,0,0,0};
  #pragma unroll 4
  for(int i = 0; i < 128; i++){
    half4 hv = cpx[(size_t)i * (DD / 4)];
    float w = ws_[i], bt = bs_[i];
    float rr[4] = {(float)hv.x, (float)hv.y, (float)hv.z, (float)hv.w};
    #pragma unroll
    for(int c = 0; c < 4; c++){
      float r = rr[c];
      float p = w * r;
      r2[c] = fmaf(r, r, r2[c]);
      p2[c] = fmaf(p, p, p2[c]);
      float pb = p * bt;
      float pb2 = pb * pb;
      float p2bt = (p * p) * bt;
      if(r > 0.f){ s3p[c] += pb2; s5p[c] += p2bt; } else { s3m[c] += pb2; s5m[c] += p2bt; }
    }
  }
  int d = tid * 4;
  float* base = stats + (size_t)b * 6 * DD + d;
  #pragma unroll
  for(int c = 0; c < 4; c++){
    atomicAdd(base + 0 * DD + c, r2[c]);
    atomicAdd(base + 1 * DD + c, p2[c]);
    atomicAdd(base + 2 * DD + c, s3p[c]);
    atomicAdd(base + 3 * DD + c, s3m[c]);
    atomicAdd(base + 4 * DD + c, s5p[c]);
    atomicAdd(base + 5 * DD + c, s5m[c]);
  }
}

// K5: per-row scalar chain -> U, Vp, Vm (exact reference EPS/clip semantics)
__global__ void k_finish(const float* __restrict__ stats, const float* __restrict__ ae,
                         const float* __restrict__ btn, const float* __restrict__ cp,
                         float* __restrict__ rowsc){
  int row = blockIdx.x * 256 + threadIdx.x;     // row = b*DD + d
  int b = row >> 10;
  int d = row & (DD - 1);
  float c = cp[0], sc = sqrtf(c), maxn = (1.f - 4e-3f) / sc;
  const float* st = stats + (size_t)b * 6 * DD + d;
  float r2 = st[0], p2 = st[DD], s3p = st[2 * DD], s3m = st[3 * DD], s5p = st[4 * DD], s5m = st[5 * DD];
  float sp2 = sqrtf(p2);
  // mobius_pointwise_mul(aw, ctx_col) + project  -> mix = beta * p
  float xn  = fmaxf(sqrtf(r2), 1e-15f);
  float wxn = fmaxf(sp2, 1e-15f);
  float at1 = artanh_c(sc * xn);
  float alpha = tanhf(wxn / xn * at1) / (wxn * sc);
  float n1 = fmaxf(alpha * sp2, 1e-15f);
  float beta = alpha * (n1 > maxn ? maxn / n1 : 1.f);
  // mobius_pointwise_mul(ae, mix) + project  -> tmp = g * p
  float aeb = ae[b];
  float mixn_raw = beta * sp2;
  float xn2  = fmaxf(mixn_raw, 1e-15f);
  float wxn2 = fmaxf(fabsf(aeb) * mixn_raw, 1e-15f);
  float at2 = artanh_c(sc * xn2);
  float coef_t = tanhf(wxn2 / xn2 * at2) * aeb * beta / (wxn2 * sc);
  float n2 = fmaxf(fabsf(coef_t) * sp2, 1e-15f);
  float g = coef_t * (n2 > maxn ? maxn / n2 : 1.f);
  // mobius_pointwise_mul(tmp, bt) + project  -> tmp2 = k * (p .* bt)
  float s3 = s3p + s3m;
  float sq3 = sqrtf(s3);
  float xn3 = btn[b];
  float wxn3 = fmaxf(fabsf(g) * sq3, 1e-15f);
  float at3 = artanh_c(sc * xn3);
  float coef2 = tanhf(wxn3 / xn3 * at3) * g / (wxn3 * sc);
  float n3 = fmaxf(fabsf(coef2) * sq3, 1e-15f);
  float k = coef2 * (n3 > maxn ? maxn / n3 : 1.f);
  // term2 = relu(k * p .* bt): nonzero where sign(r) == sign(k)
  bool kp = k > 0.f;
  float ssel  = kp ? s3p : s3m;
  float s5sel = kp ? s5p : s5m;
  float y2 = k * k * ssel;
  float xy = beta * k * s5sel;
  float x2 = beta * beta * p2;
  float A  = 1.f + 2.f * c * xy + c * y2;
  float Bc = 1.f - c * x2;
  float den = 1.f + 2.f * c * xy + c * c * x2 * y2;
  den = fmaxf(den, 1e-15f);
  float U0 = A * beta / den;
  float V0 = Bc * k / den;
  float nf2 = U0 * U0 * p2 + 2.f * U0 * V0 * s5sel + V0 * V0 * ssel;
  float nf = fmaxf(sqrtf(nf2), 1e-15f);
  float s4 = nf > maxn ? maxn / nf : 1.f;
  float U = U0 * s4, V = V0 * s4;
  float4* out4 = (float4*)(rowsc + (size_t)row * 4);
  *out4 = make_float4(U, kp ? V : 0.f, kp ? 0.f : V, 0.f);
}

// K6 (fused, fp16 ctx, no ctx LDS): 32 rows per block.
//   phase 1: colsum per row (wave-per-row, global fp16 reads) -> lam
//   phase 2: nom partial per d-quad (re-read, L2-hot), atomicAdd (nom pre-zeroed)
__global__ __launch_bounds__(256) void k_mixagg(const _Float16* __restrict__ ctx16,
                         const float* __restrict__ awt, const float* __restrict__ btt,
                         const float* __restrict__ rowsc, const float* __restrict__ cp,
                         float* __restrict__ lam_out, float* __restrict__ nom){
  __shared__ float aw_s[32], bt_s[32], lam_s[32];
  int b = blockIdx.y;
  int l0 = blockIdx.x * 32;
  int tid = threadIdx.x, wave = tid >> 6, lane = tid & 63;
  float c = cp[0];
  if(tid < 32){ aw_s[tid] = awt[b * LL + l0 + tid]; bt_s[tid] = btt[b * LL + l0 + tid]; }
  // preload rowsc: wave-layout (phase 1) d=(it*64+lane)*4+j
  float U1[4][4], Vp1[4][4], Vm1[4][4];
  const float4* rp = (const float4*)rowsc + (size_t)b * DD;
  #pragma unroll
  for(int it = 0; it < 4; it++){
    int d4 = it * 64 + lane;
    #pragma unroll
    for(int j = 0; j < 4; j++){
      float4 t = rp[d4 * 4 + j];
      U1[it][j] = t.x; Vp1[it][j] = t.y; Vm1[it][j] = t.z;
    }
  }
  // preload rowsc: quad-layout (phase 2) d=tid*4+j
  float U2[4], Vp2[4], Vm2[4];
  #pragma unroll
  for(int j = 0; j < 4; j++){
    float4 t = rp[tid * 4 + j];
    U2[j] = t.x; Vp2[j] = t.y; Vm2[j] = t.z;
  }
  __syncthreads();
  const half4* cb = (const half4*)(ctx16 + (size_t)b * LL * DD);
  // phase 1: wave w handles rows w, w+4, ..., w+28
  #pragma unroll
  for(int rr = 0; rr < 8; rr++){
    int r = wave + rr * 4;
    int l = l0 + r;
    float w = aw_s[r], bt = bt_s[r];
    float acc = 0.f;
    #pragma unroll
    for(int it = 0; it < 4; it++){
      half4 hv = cb[(size_t)l * (DD / 4) + it * 64 + lane];
      float rx[4] = {(float)hv.x, (float)hv.y, (float)hv.z, (float)hv.w};
      #pragma unroll
      for(int j = 0; j < 4; j++){
        float rc = rx[j];
        float p = w * rc;
        float t = rc > 0.f ? Vp1[it][j] : Vm1[it][j];
        float mv = p * (U1[it][j] + bt * t);
        acc = fmaf(mv, mv, acc);
      }
    }
    acc = wave_sum(acc);
    if(lane == 0){
      float lv = 2.f / fmaxf(1.f - c * acc, 1e-15f);
      lam_s[r] = lv;
      lam_out[b * LL + l] = lv;
    }
  }
  __syncthreads();
  // phase 2: thread owns d-quad, accumulate nom over 32 rows (reads are L2-hot)
  float acc2[4] = {0, 0, 0, 0};
  #pragma unroll 4
  for(int r = 0; r < 32; r++){
    float w = aw_s[r], bt = bt_s[r], lv = lam_s[r];
    half4 hv = cb[(size_t)(l0 + r) * (DD / 4) + tid];
    float rx[4] = {(float)hv.x, (float)hv.y, (float)hv.z, (float)hv.w};
    #pragma unroll
    for(int j = 0; j < 4; j++){
      float rc = rx[j];
      float p = w * rc;
      float t = rc > 0.f ? Vp2[j] : Vm2[j];
      float mv = p * (U2[j] + bt * t);
      acc2[j] = fmaf(lv, mv, acc2[j]);
    }
  }
  #pragma unroll
  for(int j = 0; j < 4; j++) atomicAdd(nom + (size_t)b * DD + tid * 4 + j, acc2[j]);
}

// K7a: den from lam; tm = nom/den; midpoint half-scalar-mul; logmap0; combined = [mixl, q]
__global__ void k_mid(const float* __restrict__ nom, const float* __restrict__ lam,
                      const float* __restrict__ qv, const float* __restrict__ cp,
                      float* __restrict__ comb){
  __shared__ float red[16];
  int b = blockIdx.x, tid = threadIdx.x;
  float c = cp[0], sc = sqrtf(c);
  float lv = lam[b * LL + tid];
  float dsum = block_sum(lv - 1.f, red);
  float den = dsum >= 0.f ? fmaxf(dsum, 1e-10f) : fminf(dsum, -1e-10f);
  float tm = nom[b * DD + tid] / den;
  float S = block_sum(tm * tm, red);
  float n = fmaxf(sqrtf(S), 1e-15f);
  float at = artanh_c(sc * n);
  float mu = tanhf(0.5f * at) / (sc * n);
  float n2 = fmaxf(mu * sqrtf(S), 1e-15f);
  float nu = artanh_c(sc * n2) / (sc * n2);
  comb[b * 2 * DD + tid] = nu * mu * tm;
  comb[b * 2 * DD + DD + tid] = qv[b * DD + tid];
}

// K7b: out[b,d] = tanh(dot(comb[b,:], Wout[d,:])); wave owns d, loops 16 b; Wout row in regs
__global__ void k_out(const float* __restrict__ comb, const float* __restrict__ Wout,
                      float* __restrict__ outp){
  int wave = threadIdx.x >> 6, lane = threadIdx.x & 63;
  int d = blockIdx.x * 4 + wave;
  int b0 = blockIdx.y * 16;
  const float4* Wr = (const float4*)(Wout + (size_t)d * 2 * DD);
  float4 w[8];
  #pragma unroll
  for(int j = 0; j < 8; j++) w[j] = Wr[j * 64 + lane];
  for(int bb = 0; bb < 16; bb++){
    int b = b0 + bb;
    const float4* cb = (const float4*)(comb + (size_t)b * 2 * DD);
    float acc = 0.f;
    #pragma unroll
    for(int j = 0; j < 8; j++){
      float4 v = cb[j * 64 + lane];
      acc += w[j].x * v.x + w[j].y * v.y + w[j].z * v.z + w[j].w * v.w;
    }
    acc = wave_sum(acc);
    if(lane == 0) outp[b * DD + d] = tanhf(acc);
  }
}

extern "C" void kernel_launch(void* const* d_in, const int* in_sizes, int n_in,
                              void* d_out, int out_size, void* d_ws, size_t ws_size,
                              hipStream_t stream) {
  const float* query = (const float*)d_in[0];
  const float* ctx   = (const float*)d_in[1];
  const float* dt    = (const float*)d_in[2];
  const float* cp    = (const float*)d_in[3];
  const float* Win   = (const float*)d_in[4];
  const float* Wout  = (const float*)d_in[5];
  const float* ae    = (const float*)d_in[6];
  const float* ab    = (const float*)d_in[7];
  float* out = (float*)d_out;
  float* ws  = (float*)d_ws;

  // ws layout (floats)
  float* q_      = ws;                 // 65536
  float* awt_    = ws + 65536;         // 65536
  float* btt_    = ws + 131072;        // 65536
  float* btn_    = ws + 196608;        // 64
  float* scores_ = ws + 196672;        // 65536  (reused as lam)
  float* stats_  = ws + 262208;        // 393216 [b][6][D] (reused as comb)
  float* nom_    = ws + 655424;        // 65536
  float* rowsc_  = ws + 720960;        // 262144 [row][4] = (U,Vp,Vm,0)
  _Float16* ctx16_ = (_Float16*)(ws + 983104); // 64M halves = 128 MB
  float* lam_  = scores_;
  float* comb_ = stats_;

  // zero only the atomic accumulators: stats | nom (contiguous)
  hipMemsetAsync(stats_, 0, (size_t)(393216 + 65536) * sizeof(float), stream);

  k_qproj     <<<dim3(256, 4),  256,  0, stream>>>(query, Win, q_);
  k_scores    <<<dim3(256, BB), 256,  0, stream>>>(q_, ctx, scores_, ctx16_);
  k_softmax_tr<<<BB,            1024, 0, stream>>>(scores_, dt, ab, cp, awt_, out + BB * DD, btt_, btn_);
  k_stats     <<<dim3(BB, 8),   256,  0, stream>>>(ctx16_, awt_, btt_, stats_);
  k_finish    <<<256,           256,  0, stream>>>(stats_, ae, btn_, cp, rowsc_);
  k_mixagg    <<<dim3(32, BB),  256,  0, stream>>>(ctx16_, awt_, btt_, rowsc_, cp, lam_, nom_);
  k_mid       <<<BB,            1024, 0, stream>>>(nom_, lam_, q_, cp, comb_);
  k_out       <<<dim3(256, 4),  256,  0, stream>>>(comb_, Wout, out);
}